// Round 11
// baseline (1410.802 us; speedup 1.0000x reference)
//
#include <hip/hip_runtime.h>

#define TT 2048
#define BB 64
#define HH 256   // EMB == HID == 256

typedef _Float16 half2_t __attribute__((ext_vector_type(2)));
typedef _Float16 half8_t __attribute__((ext_vector_type(8)));
typedef float f32x4 __attribute__((ext_vector_type(4)));
typedef int i32x4 __attribute__((ext_vector_type(4)));

static __device__ __forceinline__ float dot2i(int h, int w, float acc) {
  return __builtin_amdgcn_fdot2(__builtin_bit_cast(half2_t, h),
                                __builtin_bit_cast(half2_t, w), acc, false);
}

// ---------------------------------------------------------------------------
// prep: transpose + fp16-convert W_ih and W_hh into [N][K] row-major.
// ---------------------------------------------------------------------------
__global__ void prep_kernel(const float* __restrict__ Wih, const float* __restrict__ Whh,
                            _Float16* __restrict__ WihT, _Float16* __restrict__ WhhT) {
  const int n = blockIdx.x;   // output column
  const int k = threadIdx.x;  // input row
  WihT[n * HH + k] = (_Float16)Wih[k * HH + n];
  WhhT[n * HH + k] = (_Float16)Whh[k * HH + n];
}

// ---------------------------------------------------------------------------
// Part A: U[t][b][n] = (emb[source[b][t]] @ W_ih)[n] + b_ih[n] + b_hh[n], fp16.
// (unchanged — verified correct; scan dominates runtime)
// ---------------------------------------------------------------------------
__global__ __launch_bounds__(256, 2) void embed_gemm_kernel(
    const int* __restrict__ source, const float* __restrict__ emb,
    const _Float16* __restrict__ WihT, const float* __restrict__ b_ih,
    const float* __restrict__ b_hh, _Float16* __restrict__ U) {
  const int t = blockIdx.x;
  const int nbase = blockIdx.y * 64;
  __shared__ __align__(16) _Float16 Bs[64][280];

  const int tid = threadIdx.x;
  for (int c = tid; c < 64 * 32; c += 256) {
    const int n = c >> 5;
    const int ko = (c & 31) * 8;
    *(half8_t*)&Bs[n][ko] = *(const half8_t*)(WihT + (size_t)(nbase + n) * HH + ko);
  }
  __syncthreads();

  const int lane = tid & 63;
  const int wave = tid >> 6;
  const int row16 = lane & 15;
  const int quad = lane >> 4;
  const int b = wave * 16 + row16;              // A-fragment row = batch
  const int src = source[b * TT + t];           // source is [B][T]
  const float* arow = emb + (size_t)src * HH + quad * 8;

  f32x4 acc[4];
#pragma unroll
  for (int ct = 0; ct < 4; ++ct) acc[ct] = (f32x4){0.f, 0.f, 0.f, 0.f};

#pragma unroll
  for (int kt = 0; kt < 8; ++kt) {
    const float4 x0 = *(const float4*)(arow + kt * 32);
    const float4 x1 = *(const float4*)(arow + kt * 32 + 4);
    half8_t af;
    af[0] = (_Float16)x0.x; af[1] = (_Float16)x0.y;
    af[2] = (_Float16)x0.z; af[3] = (_Float16)x0.w;
    af[4] = (_Float16)x1.x; af[5] = (_Float16)x1.y;
    af[6] = (_Float16)x1.z; af[7] = (_Float16)x1.w;
#pragma unroll
    for (int ct = 0; ct < 4; ++ct) {
      const half8_t bf = *(const half8_t*)&Bs[ct * 16 + row16][quad * 8 + kt * 32];
      acc[ct] = __builtin_amdgcn_mfma_f32_16x16x32_f16(af, bf, acc[ct], 0, 0, 0);
    }
  }

#pragma unroll
  for (int ct = 0; ct < 4; ++ct) {
    const int nn = nbase + ct * 16 + row16;     // C col = lane&15
    const float bias = b_ih[nn] + b_hh[nn];
#pragma unroll
    for (int r = 0; r < 4; ++r) {
      const int bb = wave * 16 + quad * 4 + r;  // C row = quad*4 + reg
      U[((size_t)t * BB + bb) * HH + nn] = (_Float16)(acc[ct][r] + bias);
    }
  }
}

// ---------------------------------------------------------------------------
// Part B: recurrence — HYBRID MFMA + fdot2 (both pipes, m114 co-issue).
//   R9/R10 model: per-CU matrix pipe does 128 MFMA/step (16x M-broadcast
//   waste) = ~512 cy — the structural floor of pure-MFMA. fdot2 has no
//   M-waste (floor 256 cy) but 128 weight regs spill. Hybrid: MFMA covers
//   n in [64,256) (wave w: 3 tiles, 24 MFMA -> CU matrix 384 cy, weights
//   96 regs "+a" AGPR), fdot2 covers n in [0,64) (wave w: 16 outputs,
//   lane jo=l>>2,kk=l&3: 1 output x k-quarter = 32 fdot2, weights only
//   32 ints "+v"). VALU (~230 cy) hides under the matrix phase.
//   u moved to LDS (double-buffered 8-step chunks, coalesced staging) —
//   arch working set ~126 regs, under the allocator's proven 132 grant.
// ---------------------------------------------------------------------------
__global__ __launch_bounds__(256)
__attribute__((amdgpu_waves_per_eu(1, 1)))
void rnn_scan_kernel(
    const _Float16* __restrict__ U, const _Float16* __restrict__ WhhT,
    float* __restrict__ out) {
  const int b = blockIdx.x;
  const int tid = threadIdx.x;
  const int w = tid >> 6;
  const int l = tid & 63;
  const int col = l & 15, quad = l >> 4;   // MFMA roles
  const int jo = l >> 2, kk = l & 3;       // fdot2 roles

  __shared__ __align__(16) _Float16 hbuf[2][HH];        // 1 KB ping-pong h
  __shared__ __align__(16) _Float16 ubuf[2][8 * HH];    // 2 x 4 KB u chunks

  // --- MFMA weights: tiles n0 = 64 + 48w + 16tt, tt in {0,1,2} ---
  half8_t wb[3][8];
#pragma unroll
  for (int tt = 0; tt < 3; ++tt) {
    const _Float16* base = WhhT + (size_t)(64 + 48 * w + 16 * tt + col) * HH + quad * 8;
#pragma unroll
    for (int c = 0; c < 8; ++c) wb[tt][c] = *(const half8_t*)(base + 32 * c);
  }
  asm volatile("" : "+a"(wb[0][0]), "+a"(wb[0][1]), "+a"(wb[0][2]), "+a"(wb[0][3]),
                    "+a"(wb[0][4]), "+a"(wb[0][5]), "+a"(wb[0][6]), "+a"(wb[0][7]),
                    "+a"(wb[1][0]), "+a"(wb[1][1]), "+a"(wb[1][2]), "+a"(wb[1][3]),
                    "+a"(wb[1][4]), "+a"(wb[1][5]), "+a"(wb[1][6]), "+a"(wb[1][7]));
  asm volatile("" : "+a"(wb[2][0]), "+a"(wb[2][1]), "+a"(wb[2][2]), "+a"(wb[2][3]),
                    "+a"(wb[2][4]), "+a"(wb[2][5]), "+a"(wb[2][6]), "+a"(wb[2][7]));

  // --- fdot2 weights: output j = 16w+jo, k-quarter kk, rotated chunks ---
  // chunk c' = (i+2kk)&7 -> the 4 kk-groups hit disjoint bank groups (R4).
  i32x4 wr[8];
  {
    const _Float16* base = WhhT + (size_t)(16 * w + jo) * HH + 64 * kk;
#pragma unroll
    for (int i = 0; i < 8; ++i) wr[i] = *(const i32x4*)(base + 8 * ((i + 2 * kk) & 7));
  }
  asm volatile("" : "+v"(wr[0]), "+v"(wr[1]), "+v"(wr[2]), "+v"(wr[3]),
                    "+v"(wr[4]), "+v"(wr[5]), "+v"(wr[6]), "+v"(wr[7]));

  hbuf[0][tid] = (_Float16)0.f;  // h0 = 0

  const int n_m = (64 + 48 * w + 16 * quad + col) & 255;  // masked: quad==3 unused
  const int n_d = 16 * w + jo;

  // preload u chunk 0 into ubuf[0]
  {
#pragma unroll
    for (int s = 0; s < 8; ++s)
      ubuf[0][s * HH + tid] = U[((size_t)s * BB + b) * HH + tid];
  }
  float hn_m = 0.f, hn_d = 0.f;
  __syncthreads();

  for (int tc = 0; tc < TT; tc += 8) {
    // Issue next-chunk u global loads NOW (drained by step-0's barrier,
    // ~1 step in flight -> amortized ~30 cy/step).
    const int tn = (tc + 8) & (TT - 1);
    _Float16 ut[8];
#pragma unroll
    for (int s = 0; s < 8; ++s)
      ut[s] = U[((size_t)(tn + s) * BB + b) * HH + tid];

#pragma unroll
    for (int s = 0; s < 8; ++s) {
      const int t = tc + s;
      const _Float16* hb = hbuf[t & 1];

      // ---- MFMA A-frags: broadcast h; quads on disjoint banks ----
      half8_t ha[8];
#pragma unroll
      for (int c = 0; c < 8; ++c) ha[c] = *(const half8_t*)(hb + 32 * c + quad * 8);
      // ---- fdot2 h-quarter, bank-rotated ----
      i32x4 hv[8];
#pragma unroll
      for (int i = 0; i < 8; ++i)
        hv[i] = *(const i32x4*)(hb + 64 * kk + 8 * ((i + 2 * kk) & 7));
      asm volatile("" : "+v"(ha[0]), "+v"(ha[1]), "+v"(ha[2]), "+v"(ha[3]),
                        "+v"(ha[4]), "+v"(ha[5]), "+v"(ha[6]), "+v"(ha[7]));
      asm volatile("" : "+v"(hv[0]), "+v"(hv[1]), "+v"(hv[2]), "+v"(hv[3]),
                        "+v"(hv[4]), "+v"(hv[5]), "+v"(hv[6]), "+v"(hv[7]));

      // ---- matrix pipe: 24 MFMA in 3 k-chains ----
      f32x4 cacc[3];
#pragma unroll
      for (int tt = 0; tt < 3; ++tt) cacc[tt] = (f32x4){0.f, 0.f, 0.f, 0.f};
#pragma unroll
      for (int c = 0; c < 8; ++c)
#pragma unroll
        for (int tt = 0; tt < 3; ++tt)
          cacc[tt] = __builtin_amdgcn_mfma_f32_16x16x32_f16(ha[c], wb[tt][c], cacc[tt], 0, 0, 0);

      // ---- VALU pipe: 32 fdot2 in 4 chains (co-issues with MFMA) ----
      float pa0 = 0.f, pa1 = 0.f, pa2 = 0.f, pa3 = 0.f;
#pragma unroll
      for (int i = 0; i < 8; ++i) {
        const i32x4 h4 = hv[i];
        const i32x4 w4 = wr[i];
        pa0 = dot2i(h4[0], w4[0], pa0);
        pa1 = dot2i(h4[1], w4[1], pa1);
        pa2 = dot2i(h4[2], w4[2], pa2);
        pa3 = dot2i(h4[3], w4[3], pa3);
      }
      float pa = (pa0 + pa1) + (pa2 + pa3);
      // reduce over kk (quad lanes) via DPP quad_perm
      pa += __int_as_float(__builtin_amdgcn_mov_dpp(__float_as_int(pa), 0xB1, 0xF, 0xF, true));
      pa += __int_as_float(__builtin_amdgcn_mov_dpp(__float_as_int(pa), 0x4E, 0xF, 0xF, true));

      // ---- finalize MFMA output (quad<3): n_m; all C rows equal ----
      float ym = cacc[0][0];
      ym = (quad == 1) ? cacc[1][0] : ym;
      ym = (quad == 2) ? cacc[2][0] : ym;
      const float um = (float)ubuf[(tc >> 3) & 1][s * HH + n_m];
      const float am = um + ym;
      const float em = __builtin_amdgcn_exp2f(am * 2.885390081777927f);
      hn_m = 1.f - 2.f * __builtin_amdgcn_rcpf(em + 1.f);
      if (quad < 3) hbuf[(t + 1) & 1][n_m] = (_Float16)hn_m;

      // ---- finalize fdot2 output (kk==0): n_d ----
      const float ud = (float)ubuf[(tc >> 3) & 1][s * HH + n_d];
      const float ad = ud + pa;
      const float ed = __builtin_amdgcn_exp2f(ad * 2.885390081777927f);
      hn_d = 1.f - 2.f * __builtin_amdgcn_rcpf(ed + 1.f);
      if (kk == 0) hbuf[(t + 1) & 1][n_d] = (_Float16)hn_d;

      if (s == 0) {
        // stage next-chunk u into the other ubuf before this barrier
#pragma unroll
        for (int q = 0; q < 8; ++q)
          ubuf[((tc >> 3) + 1) & 1][q * HH + tid] = ut[q];
      }
      __syncthreads();  // single per-step barrier
    }
  }
  if (quad < 3) out[(size_t)b * HH + n_m] = hn_m;
  if (kk == 0)  out[(size_t)b * HH + n_d] = hn_d;
}

// ---------------------------------------------------------------------------
extern "C" void kernel_launch(void* const* d_in, const int* in_sizes, int n_in,
                              void* d_out, int out_size, void* d_ws, size_t ws_size,
                              hipStream_t stream) {
  const int*   source = (const int*)d_in[0];
  const float* emb    = (const float*)d_in[1];
  const float* Wih    = (const float*)d_in[2];
  const float* Whh    = (const float*)d_in[3];
  const float* bih    = (const float*)d_in[4];
  const float* bhh    = (const float*)d_in[5];
  float* out = (float*)d_out;

  char* ws = (char*)d_ws;
  _Float16* U    = (_Float16*)ws;                    // 2048*64*256*2 = 67,108,864 B
  _Float16* WihT = (_Float16*)(ws + 67108864);       // 131,072 B
  _Float16* WhhT = (_Float16*)(ws + 67239936);       // 131,072 B (total ~67.4 MB)

  prep_kernel<<<dim3(256), dim3(256), 0, stream>>>(Wih, Whh, WihT, WhhT);
  embed_gemm_kernel<<<dim3(TT, 4), dim3(256), 0, stream>>>(source, emb, WihT, bih, bhh, U);
  rnn_scan_kernel<<<dim3(BB), dim3(256), 0, stream>>>(U, WhhT, out);
}

// Round 12
// 1012.527 us; speedup vs baseline: 1.3933x; 1.3933x over previous
//
#include <hip/hip_runtime.h>

#define TT 2048
#define BB 64
#define HH 256   // EMB == HID == 256

typedef _Float16 half2_t __attribute__((ext_vector_type(2)));
typedef _Float16 half8_t __attribute__((ext_vector_type(8)));
typedef float f32x4 __attribute__((ext_vector_type(4)));
typedef int i32x4 __attribute__((ext_vector_type(4)));

// ---------------------------------------------------------------------------
// prep: transpose + fp16-convert W_ih and W_hh into [N][K] row-major.
// ---------------------------------------------------------------------------
__global__ void prep_kernel(const float* __restrict__ Wih, const float* __restrict__ Whh,
                            _Float16* __restrict__ WihT, _Float16* __restrict__ WhhT) {
  const int n = blockIdx.x;   // output column
  const int k = threadIdx.x;  // input row
  WihT[n * HH + k] = (_Float16)Wih[k * HH + n];
  WhhT[n * HH + k] = (_Float16)Whh[k * HH + n];
}

// ---------------------------------------------------------------------------
// Part A: U[t][b][n] = (emb[source[b][t]] @ W_ih)[n] + b_ih[n] + b_hh[n], fp16.
// (unchanged — verified correct; scan dominates runtime)
// ---------------------------------------------------------------------------
__global__ __launch_bounds__(256, 2) void embed_gemm_kernel(
    const int* __restrict__ source, const float* __restrict__ emb,
    const _Float16* __restrict__ WihT, const float* __restrict__ b_ih,
    const float* __restrict__ b_hh, _Float16* __restrict__ U) {
  const int t = blockIdx.x;
  const int nbase = blockIdx.y * 64;
  __shared__ __align__(16) _Float16 Bs[64][280];

  const int tid = threadIdx.x;
  for (int c = tid; c < 64 * 32; c += 256) {
    const int n = c >> 5;
    const int ko = (c & 31) * 8;
    *(half8_t*)&Bs[n][ko] = *(const half8_t*)(WihT + (size_t)(nbase + n) * HH + ko);
  }
  __syncthreads();

  const int lane = tid & 63;
  const int wave = tid >> 6;
  const int row16 = lane & 15;
  const int quad = lane >> 4;
  const int b = wave * 16 + row16;              // A-fragment row = batch
  const int src = source[b * TT + t];           // source is [B][T]
  const float* arow = emb + (size_t)src * HH + quad * 8;

  f32x4 acc[4];
#pragma unroll
  for (int ct = 0; ct < 4; ++ct) acc[ct] = (f32x4){0.f, 0.f, 0.f, 0.f};

#pragma unroll
  for (int kt = 0; kt < 8; ++kt) {
    const float4 x0 = *(const float4*)(arow + kt * 32);
    const float4 x1 = *(const float4*)(arow + kt * 32 + 4);
    half8_t af;
    af[0] = (_Float16)x0.x; af[1] = (_Float16)x0.y;
    af[2] = (_Float16)x0.z; af[3] = (_Float16)x0.w;
    af[4] = (_Float16)x1.x; af[5] = (_Float16)x1.y;
    af[6] = (_Float16)x1.z; af[7] = (_Float16)x1.w;
#pragma unroll
    for (int ct = 0; ct < 4; ++ct) {
      const half8_t bf = *(const half8_t*)&Bs[ct * 16 + row16][quad * 8 + kt * 32];
      acc[ct] = __builtin_amdgcn_mfma_f32_16x16x32_f16(af, bf, acc[ct], 0, 0, 0);
    }
  }

#pragma unroll
  for (int ct = 0; ct < 4; ++ct) {
    const int nn = nbase + ct * 16 + row16;     // C col = lane&15
    const float bias = b_ih[nn] + b_hh[nn];
#pragma unroll
    for (int r = 0; r < 4; ++r) {
      const int bb = wave * 16 + quad * 4 + r;  // C row = quad*4 + reg
      U[((size_t)t * BB + bb) * HH + nn] = (_Float16)(acc[ct][r] + bias);
    }
  }
}

// ---------------------------------------------------------------------------
// Part B: recurrence via MFMA, 8 waves so 2 waves share each SIMD.
//   R9/R10 model: per-SIMD matrix floor = 32 MFMA x ~16 cy = 512 cy/step
//   (M-broadcast waste); at 1 wave/SIMD the OTHER ~440 cy (h-read latency,
//   finalize tail, barrier skew) is fully exposed — wall 950 cy. Here:
//   8 waves, wave w owns n-tiles {2w,2w+1} (16 MFMA/wave) -> per-SIMD
//   matrix work unchanged, but the co-resident wave's MFMAs hide the
//   partner's latencies (m114 co-schedule). Weights: 16 quads/wave "+a"
//   (AGPR, MFMA-native). Arch set ~70 regs — smallest of any round, sized
//   to survive even a stingy allocator grant (R7 lesson).
//   Finalize: all 4 C-rows identical; quad q<2 writes n = 32w+16q+col.
//   u in registers, 8-step prefetch chunks (R8 mechanism). 1 barrier/step.
// ---------------------------------------------------------------------------
__global__ __launch_bounds__(512)
__attribute__((amdgpu_waves_per_eu(2, 2)))
void rnn_scan_kernel(
    const _Float16* __restrict__ U, const _Float16* __restrict__ WhhT,
    float* __restrict__ out) {
  const int b = blockIdx.x;
  const int tid = threadIdx.x;
  const int w = tid >> 6;    // wave in [0,8): owns n in [32w, 32w+32)
  const int l = tid & 63;
  const int col = l & 15;
  const int quad = l >> 4;

  __shared__ __align__(16) _Float16 hbuf[2][HH];  // 1 KB ping-pong

  // wb[tt][c]: B-frag for n-tile 32w+16tt, k-chunk c (16B aligned reads).
  half8_t wb[2][8];
#pragma unroll
  for (int tt = 0; tt < 2; ++tt) {
    const _Float16* base = WhhT + (size_t)(32 * w + 16 * tt + col) * HH + quad * 8;
#pragma unroll
    for (int c = 0; c < 8; ++c) wb[tt][c] = *(const half8_t*)(base + 32 * c);
  }
  // Pin into AGPRs: one-time accvgpr_write; MFMA reads B from AGPR natively.
  asm volatile("" : "+a"(wb[0][0]), "+a"(wb[0][1]), "+a"(wb[0][2]), "+a"(wb[0][3]),
                    "+a"(wb[0][4]), "+a"(wb[0][5]), "+a"(wb[0][6]), "+a"(wb[0][7]),
                    "+a"(wb[1][0]), "+a"(wb[1][1]), "+a"(wb[1][2]), "+a"(wb[1][3]),
                    "+a"(wb[1][4]), "+a"(wb[1][5]), "+a"(wb[1][6]), "+a"(wb[1][7]));

  if (tid < HH) hbuf[0][tid] = (_Float16)0.f;  // h0 = 0

  // Lane finalizes n_u (quads 0,1 are the writers; 2,3 compute mirrors).
  const int n_u = 32 * w + 16 * (quad & 1) + col;
  const _Float16* Up = U + b * HH + n_u;  // step stride = BB*HH halfs
  _Float16 uc[8], un[8];
#pragma unroll
  for (int s = 0; s < 8; ++s) uc[s] = Up[(size_t)s * (BB * HH)];

  float hn = 0.f;
  __syncthreads();

  for (int tc = 0; tc < TT; tc += 8) {
    // Issue all next-chunk u-loads; first barrier after drains them.
    const int tn = (tc + 8) & (TT - 1);
#pragma unroll
    for (int s = 0; s < 8; ++s) un[s] = Up[(size_t)(tn + s) * (BB * HH)];

#pragma unroll
    for (int s = 0; s < 8; ++s) {
      const int t = tc + s;

      // ---- A-frags: broadcast h chunks (quads read disjoint bank groups) ----
      const _Float16* hrow = hbuf[t & 1] + quad * 8;
      half8_t ha[8];
#pragma unroll
      for (int c = 0; c < 8; ++c) ha[c] = *(const half8_t*)(hrow + 32 * c);
      // Batch: all 8 reads issue first, ONE lgkmcnt wait.
      asm volatile("" : "+v"(ha[0]), "+v"(ha[1]), "+v"(ha[2]), "+v"(ha[3]),
                        "+v"(ha[4]), "+v"(ha[5]), "+v"(ha[6]), "+v"(ha[7]));

      // ---- 16 MFMAs: 4 independent chains (2 tiles x 2 sub-accumulators) ----
      f32x4 acc[2][2];
#pragma unroll
      for (int tt = 0; tt < 2; ++tt)
#pragma unroll
        for (int p = 0; p < 2; ++p) acc[tt][p] = (f32x4){0.f, 0.f, 0.f, 0.f};
#pragma unroll
      for (int c = 0; c < 8; ++c)
#pragma unroll
        for (int tt = 0; tt < 2; ++tt)
          acc[tt][c & 1] = __builtin_amdgcn_mfma_f32_16x16x32_f16(ha[c], wb[tt][c], acc[tt][c & 1], 0, 0, 0);

      // ---- finalize: all C rows equal; quad selects its tile ----
      const float y0 = acc[0][0][0] + acc[0][1][0];
      const float y1 = acc[1][0][0] + acc[1][1][0];
      const float y = (quad & 1) ? y1 : y0;

      const float a = (float)uc[s] + y;
      // tanh(a) = 1 - 2/(exp(2a)+1)
      const float e = __builtin_amdgcn_exp2f(a * 2.885390081777927f);  // 2*log2(e)
      hn = 1.f - 2.f * __builtin_amdgcn_rcpf(e + 1.f);
      if (quad < 2) hbuf[(t + 1) & 1][n_u] = (_Float16)hn;

      __syncthreads();  // single per-step barrier
    }
#pragma unroll
    for (int s = 0; s < 8; ++s) uc[s] = un[s];
  }
  if (quad < 2) out[(size_t)b * HH + n_u] = hn;
}

// ---------------------------------------------------------------------------
extern "C" void kernel_launch(void* const* d_in, const int* in_sizes, int n_in,
                              void* d_out, int out_size, void* d_ws, size_t ws_size,
                              hipStream_t stream) {
  const int*   source = (const int*)d_in[0];
  const float* emb    = (const float*)d_in[1];
  const float* Wih    = (const float*)d_in[2];
  const float* Whh    = (const float*)d_in[3];
  const float* bih    = (const float*)d_in[4];
  const float* bhh    = (const float*)d_in[5];
  float* out = (float*)d_out;

  char* ws = (char*)d_ws;
  _Float16* U    = (_Float16*)ws;                    // 2048*64*256*2 = 67,108,864 B
  _Float16* WihT = (_Float16*)(ws + 67108864);       // 131,072 B
  _Float16* WhhT = (_Float16*)(ws + 67239936);       // 131,072 B (total ~67.4 MB)

  prep_kernel<<<dim3(256), dim3(256), 0, stream>>>(Wih, Whh, WihT, WhhT);
  embed_gemm_kernel<<<dim3(TT, 4), dim3(256), 0, stream>>>(source, emb, WihT, bih, bhh, U);
  rnn_scan_kernel<<<dim3(BB), dim3(512), 0, stream>>>(U, WhhT, out);
}

// Round 13
// 966.198 us; speedup vs baseline: 1.4602x; 1.0480x over previous
//
#include <hip/hip_runtime.h>

#define TT 2048
#define BB 64
#define HH 256   // EMB == HID == 256

typedef _Float16 half2_t __attribute__((ext_vector_type(2)));
typedef _Float16 half8_t __attribute__((ext_vector_type(8)));
typedef float f32x4 __attribute__((ext_vector_type(4)));
typedef int i32x4 __attribute__((ext_vector_type(4)));

// ---------------------------------------------------------------------------
// prep: transpose + fp16-convert W_ih and W_hh into [N][K] row-major.
// ---------------------------------------------------------------------------
__global__ void prep_kernel(const float* __restrict__ Wih, const float* __restrict__ Whh,
                            _Float16* __restrict__ WihT, _Float16* __restrict__ WhhT) {
  const int n = blockIdx.x;   // output column
  const int k = threadIdx.x;  // input row
  WihT[n * HH + k] = (_Float16)Wih[k * HH + n];
  WhhT[n * HH + k] = (_Float16)Whh[k * HH + n];
}

// ---------------------------------------------------------------------------
// Part A: U[t][b][n] = (emb[source[b][t]] @ W_ih)[n] + b_ih[n] + b_hh[n], fp16.
// (unchanged — verified correct; scan dominates runtime)
// ---------------------------------------------------------------------------
__global__ __launch_bounds__(256, 2) void embed_gemm_kernel(
    const int* __restrict__ source, const float* __restrict__ emb,
    const _Float16* __restrict__ WihT, const float* __restrict__ b_ih,
    const float* __restrict__ b_hh, _Float16* __restrict__ U) {
  const int t = blockIdx.x;
  const int nbase = blockIdx.y * 64;
  __shared__ __align__(16) _Float16 Bs[64][280];

  const int tid = threadIdx.x;
  for (int c = tid; c < 64 * 32; c += 256) {
    const int n = c >> 5;
    const int ko = (c & 31) * 8;
    *(half8_t*)&Bs[n][ko] = *(const half8_t*)(WihT + (size_t)(nbase + n) * HH + ko);
  }
  __syncthreads();

  const int lane = tid & 63;
  const int wave = tid >> 6;
  const int row16 = lane & 15;
  const int quad = lane >> 4;
  const int b = wave * 16 + row16;              // A-fragment row = batch
  const int src = source[b * TT + t];           // source is [B][T]
  const float* arow = emb + (size_t)src * HH + quad * 8;

  f32x4 acc[4];
#pragma unroll
  for (int ct = 0; ct < 4; ++ct) acc[ct] = (f32x4){0.f, 0.f, 0.f, 0.f};

#pragma unroll
  for (int kt = 0; kt < 8; ++kt) {
    const float4 x0 = *(const float4*)(arow + kt * 32);
    const float4 x1 = *(const float4*)(arow + kt * 32 + 4);
    half8_t af;
    af[0] = (_Float16)x0.x; af[1] = (_Float16)x0.y;
    af[2] = (_Float16)x0.z; af[3] = (_Float16)x0.w;
    af[4] = (_Float16)x1.x; af[5] = (_Float16)x1.y;
    af[6] = (_Float16)x1.z; af[7] = (_Float16)x1.w;
#pragma unroll
    for (int ct = 0; ct < 4; ++ct) {
      const half8_t bf = *(const half8_t*)&Bs[ct * 16 + row16][quad * 8 + kt * 32];
      acc[ct] = __builtin_amdgcn_mfma_f32_16x16x32_f16(af, bf, acc[ct], 0, 0, 0);
    }
  }

#pragma unroll
  for (int ct = 0; ct < 4; ++ct) {
    const int nn = nbase + ct * 16 + row16;     // C col = lane&15
    const float bias = b_ih[nn] + b_hh[nn];
#pragma unroll
    for (int r = 0; r < 4; ++r) {
      const int bb = wave * 16 + quad * 4 + r;  // C row = quad*4 + reg
      U[((size_t)t * BB + bb) * HH + nn] = (_Float16)(acc[ct][r] + bias);
    }
  }
}

// ---------------------------------------------------------------------------
// Part B: recurrence via MFMA (R9/R10 structure). One change vs R10:
//   the ha batch-pin forced s_waitcnt lgkmcnt(0) (~216 cy: read7 issues at
//   ~96 cy + 120 cy latency) before the FIRST MFMA. Now: issue all 8 reads,
//   then an asm memory-clobber (stops the scheduler sinking reads down to
//   their uses — the R6 serialization failure), then consume UNPINNED so
//   the compiler emits fine-grained lgkmcnt(7-c) per chunk (m97 behavior):
//   first MFMA waits only ~120 cy; reads 1-7 return under the MFMA stream.
//   Everything else identical: M-broadcast A-frag, wave w owns n in
//   [64w,64w+64), 4 tiles x 8 k-chunks = 32 MFMA/step (per-SIMD 512 cy
//   structural floor), weights "+a" AGPR, thread tid finalizes n = tid,
//   1 barrier/step, 8-step u prefetch chunks.
// ---------------------------------------------------------------------------
__global__ __launch_bounds__(256)
__attribute__((amdgpu_waves_per_eu(1, 1)))
void rnn_scan_kernel(
    const _Float16* __restrict__ U, const _Float16* __restrict__ WhhT,
    float* __restrict__ out) {
  const int b = blockIdx.x;
  const int tid = threadIdx.x;
  const int w = tid >> 6;
  const int l = tid & 63;
  const int col = l & 15;    // n within tile
  const int quad = l >> 4;   // MFMA quad / finalize tile

  __shared__ __align__(16) _Float16 hbuf[2][HH];  // 1 KB ping-pong

  // wb[tt][c]: B-frag for n-tile 64w+16tt, k-chunk c.
  half8_t wb[4][8];
#pragma unroll
  for (int tt = 0; tt < 4; ++tt) {
    const _Float16* base = WhhT + (size_t)(64 * w + 16 * tt + col) * HH + quad * 8;
#pragma unroll
    for (int c = 0; c < 8; ++c) wb[tt][c] = *(const half8_t*)(base + 32 * c);
  }
  // Pin into AGPRs: one-time accvgpr_write; MFMA reads B from AGPR natively.
  asm volatile("" : "+a"(wb[0][0]), "+a"(wb[0][1]), "+a"(wb[0][2]), "+a"(wb[0][3]),
                    "+a"(wb[0][4]), "+a"(wb[0][5]), "+a"(wb[0][6]), "+a"(wb[0][7]),
                    "+a"(wb[1][0]), "+a"(wb[1][1]), "+a"(wb[1][2]), "+a"(wb[1][3]),
                    "+a"(wb[1][4]), "+a"(wb[1][5]), "+a"(wb[1][6]), "+a"(wb[1][7]));
  asm volatile("" : "+a"(wb[2][0]), "+a"(wb[2][1]), "+a"(wb[2][2]), "+a"(wb[2][3]),
                    "+a"(wb[2][4]), "+a"(wb[2][5]), "+a"(wb[2][6]), "+a"(wb[2][7]),
                    "+a"(wb[3][0]), "+a"(wb[3][1]), "+a"(wb[3][2]), "+a"(wb[3][3]),
                    "+a"(wb[3][4]), "+a"(wb[3][5]), "+a"(wb[3][6]), "+a"(wb[3][7]));

  hbuf[0][tid] = (_Float16)0.f;  // h0 = 0

  // Thread tid finalizes output n = tid: u stream is per-thread contiguous.
  const _Float16* Up = U + b * HH + tid;  // step stride = BB*HH halfs
  _Float16 uc[8], un[8];
#pragma unroll
  for (int s = 0; s < 8; ++s) uc[s] = Up[(size_t)s * (BB * HH)];

  float hn = 0.f;
  __syncthreads();

  for (int tc = 0; tc < TT; tc += 8) {
    // Issue all next-chunk u-loads; ~1 full step in flight before the first
    // barrier's vmcnt(0) drain -> amortized ~0 cy/step.
    const int tn = (tc + 8) & (TT - 1);
#pragma unroll
    for (int s = 0; s < 8; ++s) un[s] = Up[(size_t)(tn + s) * (BB * HH)];

#pragma unroll
    for (int s = 0; s < 8; ++s) {
      const int t = tc + s;

      // ---- A-frags: broadcast h chunks; issue all 8 reads back-to-back ----
      const _Float16* hrow = hbuf[t & 1] + quad * 8;
      half8_t ha[8];
#pragma unroll
      for (int c = 0; c < 8; ++c) ha[c] = *(const half8_t*)(hrow + 32 * c);
      // Memory clobber: reads may not sink below this point (prevents the
      // R6 read-at-use serialization), but uses stay unpinned so the
      // compiler emits fine-grained lgkmcnt(7-c) per chunk.
      asm volatile("" ::: "memory");

      // ---- 32 MFMAs: 4 independent k-chains (one per n-tile) ----
      f32x4 cacc[4];
#pragma unroll
      for (int tt = 0; tt < 4; ++tt) cacc[tt] = (f32x4){0.f, 0.f, 0.f, 0.f};
#pragma unroll
      for (int c = 0; c < 8; ++c)
#pragma unroll
        for (int tt = 0; tt < 4; ++tt)
          cacc[tt] = __builtin_amdgcn_mfma_f32_16x16x32_f16(ha[c], wb[tt][c], cacc[tt], 0, 0, 0);

      // ---- finalize: quad q owns tile q  =>  n = 64w + 16q + col = tid ----
      float y = cacc[0][0];
      y = (quad == 1) ? cacc[1][0] : y;
      y = (quad == 2) ? cacc[2][0] : y;
      y = (quad == 3) ? cacc[3][0] : y;

      const float a = (float)uc[s] + y;
      // tanh(a) = 1 - 2/(exp(2a)+1)
      const float e = __builtin_amdgcn_exp2f(a * 2.885390081777927f);  // 2*log2(e)
      hn = 1.f - 2.f * __builtin_amdgcn_rcpf(e + 1.f);
      hbuf[(t + 1) & 1][tid] = (_Float16)hn;

      __syncthreads();  // single per-step barrier
    }
#pragma unroll
    for (int s = 0; s < 8; ++s) uc[s] = un[s];
  }
  out[(size_t)b * HH + tid] = hn;
}

// ---------------------------------------------------------------------------
extern "C" void kernel_launch(void* const* d_in, const int* in_sizes, int n_in,
                              void* d_out, int out_size, void* d_ws, size_t ws_size,
                              hipStream_t stream) {
  const int*   source = (const int*)d_in[0];
  const float* emb    = (const float*)d_in[1];
  const float* Wih    = (const float*)d_in[2];
  const float* Whh    = (const float*)d_in[3];
  const float* bih    = (const float*)d_in[4];
  const float* bhh    = (const float*)d_in[5];
  float* out = (float*)d_out;

  char* ws = (char*)d_ws;
  _Float16* U    = (_Float16*)ws;                    // 2048*64*256*2 = 67,108,864 B
  _Float16* WihT = (_Float16*)(ws + 67108864);       // 131,072 B
  _Float16* WhhT = (_Float16*)(ws + 67239936);       // 131,072 B (total ~67.4 MB)

  prep_kernel<<<dim3(256), dim3(256), 0, stream>>>(Wih, Whh, WihT, WhhT);
  embed_gemm_kernel<<<dim3(TT, 4), dim3(256), 0, stream>>>(source, emb, WihT, bih, bhh, U);
  rnn_scan_kernel<<<dim3(BB), dim3(256), 0, stream>>>(U, WhhT, out);
}